// Round 6
// baseline (736.827 us; speedup 1.0000x reference)
//
#include <hip/hip_runtime.h>
#include <hip/hip_bf16.h>

typedef __hip_bfloat16 bf16;
typedef short s16x8 __attribute__((ext_vector_type(8)));
typedef unsigned short u16x8 __attribute__((ext_vector_type(8)));
typedef float f32x4 __attribute__((ext_vector_type(4)));

#define T_TOK 2048
#define HDIM  2048
#define NEXP  64
#define IDIM  768
#define TOPK  8
#define OUT_OFF (T_TOK * HDIM)
#define NPAIR (T_TOK * TOPK)

#define WS_TOPK_IDX  0
#define WS_TOPK_W    (64 * 1024)
#define WS_PAIR_TOK  (128 * 1024)
#define WS_SLOT_OF   (192 * 1024)
#define WS_COUNTS    (256 * 1024)
#define WS_OFFSETS   (257 * 1024)
#define WS_CURSOR    (258 * 1024)
#define WS_H         (1024 * 1024)             // bf16 [NPAIR][IDIM]
#define WS_PARTIAL   (WS_H + (size_t)NPAIR * IDIM * 2)  // bf16 [NPAIR][HDIM]
#define WS_XB        WS_PARTIAL                // bf16 [T][H] (dead before partial written)

__device__ __forceinline__ float bf_to_f(unsigned short u) {
    return __uint_as_float(((unsigned int)u) << 16);
}
__device__ __forceinline__ unsigned short f2bf(float f) {
    unsigned int u = __float_as_uint(f);
    unsigned int r = (u + 0x7FFFu + ((u >> 16) & 1u)) >> 16;
    return (unsigned short)r;
}
__device__ __forceinline__ unsigned cvtpk(float lo, float hi) {
    unsigned r;
    asm("v_cvt_pk_bf16_f32 %0, %1, %2" : "=v"(r) : "v"(lo), "v"(hi));
    return r;
}

typedef const __attribute__((address_space(1))) unsigned int* gas_ptr;
typedef __attribute__((address_space(3))) unsigned int* las_ptr;
__device__ __forceinline__ void gload_lds16(const void* g, void* l) {
    __builtin_amdgcn_global_load_lds((gas_ptr)g, (las_ptr)l, 16, 0, 0);
}

// ---------------- kernel 0: x fp32 -> bf16 ----------------
__global__ __launch_bounds__(256) void xbf_kernel(const float* __restrict__ x,
                                                  unsigned short* __restrict__ xb) {
    int i = blockIdx.x * 256 + threadIdx.x;
    const float4* src = (const float4*)x + (size_t)i * 2;
    float4 a = src[0], b = src[1];
    u16x8 o;
    o[0] = f2bf(a.x); o[1] = f2bf(a.y); o[2] = f2bf(a.z); o[3] = f2bf(a.w);
    o[4] = f2bf(b.x); o[5] = f2bf(b.y); o[6] = f2bf(b.z); o[7] = f2bf(b.w);
    ((u16x8*)xb)[i] = o;
}

// ---------------- kernel 1: router logits ----------------
__global__ __launch_bounds__(256) void router_kernel(
    const float* __restrict__ x, const float* __restrict__ rw,
    float* __restrict__ logits) {
    int wave = threadIdx.x >> 6;
    int lane = threadIdx.x & 63;
    int t = blockIdx.x * 4 + wave;
    const float4* x4 = (const float4*)(x + (size_t)t * HDIM);
    float acc = 0.f;
    for (int h4 = 0; h4 < HDIM / 4; ++h4) {
        float4 xv = x4[h4];
        int h = h4 * 4;
        acc = fmaf(xv.x, rw[(h + 0) * NEXP + lane], acc);
        acc = fmaf(xv.y, rw[(h + 1) * NEXP + lane], acc);
        acc = fmaf(xv.z, rw[(h + 2) * NEXP + lane], acc);
        acc = fmaf(xv.w, rw[(h + 3) * NEXP + lane], acc);
    }
    logits[t * NEXP + lane] = acc;
}

// ---------------- kernel 2: softmax + top-8 ----------------
__global__ __launch_bounds__(64) void topk_kernel(
    const float* __restrict__ logits, int* __restrict__ topk_idx,
    float* __restrict__ topk_w, int* __restrict__ counts) {
    int t = blockIdx.x;
    int lane = threadIdx.x;
    float lg = logits[t * NEXP + lane];
    float mx = lg;
    for (int off = 32; off; off >>= 1) mx = fmaxf(mx, __shfl_xor(mx, off));
    float ex = expf(lg - mx);
    float sum = ex;
    for (int off = 32; off; off >>= 1) sum += __shfl_xor(sum, off);
    float prob = ex / sum;

    float pr = prob;
    float myv = 0.f;
    int myidx = 0;
    float ksum = 0.f;
    for (int k = 0; k < TOPK; ++k) {
        float v = pr;
        int idx = lane;
        for (int off = 32; off; off >>= 1) {
            float ov = __shfl_xor(v, off);
            int oi = __shfl_xor(idx, off);
            if (ov > v || (ov == v && oi < idx)) { v = ov; idx = oi; }
        }
        ksum += v;
        if (lane == k) { myidx = idx; myv = v; }
        if (lane == idx) pr = -1.f;
    }
    if (lane < TOPK) {
        topk_idx[t * TOPK + lane] = myidx;
        topk_w[t * TOPK + lane] = myv / ksum;
        atomicAdd(&counts[myidx], 1);
    }
}

// ---------------- kernel 3: scan ----------------
__global__ __launch_bounds__(64) void scan_kernel(
    const int* __restrict__ counts, int* __restrict__ offsets, int* __restrict__ cursor) {
    int lane = threadIdx.x;
    int c = counts[lane];
    int incl = c;
    for (int off = 1; off < 64; off <<= 1) {
        int tt = __shfl_up(incl, off);
        if (lane >= off) incl += tt;
    }
    offsets[lane] = incl - c;
    if (lane == 63) offsets[64] = incl;
    cursor[lane] = 0;
}

// ---------------- kernel 4: scatter ----------------
__global__ __launch_bounds__(256) void scatter_kernel(
    const int* __restrict__ topk_idx, const int* __restrict__ offsets,
    int* __restrict__ cursor, int* __restrict__ pair_token, int* __restrict__ slot_of) {
    int i = blockIdx.x * 256 + threadIdx.x;
    if (i >= NPAIR) return;
    int t = i >> 3;
    int e = topk_idx[i];
    int pos = atomicAdd(&cursor[e], 1);
    int slot = offsets[e] + pos;
    pair_token[slot] = t;
    slot_of[i] = slot;
}

// ================= MFMA grouped GEMMs (512 thr, 8 waves, pipelined) =========
#define BM   128
#define BKS  64
#define NKG  (HDIM / BKS)   // 32
#define NKD  (IDIM / BKS)   // 12

// pipelined step for gateup. KS: runtime step index; BV: named reg set
// (parity-static); P: compile-time buffer parity.
#define GU_STEP(KS, BV, P)                                                    \
  {                                                                           \
    /* W: cvt B_(KS) (auto counted-vmcnt wait) + ds_write to Bgu[P] */        \
    uint4 w0, w1;                                                             \
    w0.x = cvtpk(BV[0].x, BV[1].x); w0.y = cvtpk(BV[2].x, BV[3].x);           \
    w0.z = cvtpk(BV[4].x, BV[5].x); w0.w = cvtpk(BV[6].x, BV[7].x);           \
    w1.x = cvtpk(BV[0].y, BV[1].y); w1.y = cvtpk(BV[2].y, BV[3].y);           \
    w1.z = cvtpk(BV[4].y, BV[5].y); w1.w = cvtpk(BV[6].y, BV[7].y);           \
    *(uint4*)&Bgu[P][brow0 * BKS + bslot] = w0;                               \
    *(uint4*)&Bgu[P][(brow0 + 1) * BKS + bslot] = w1;                         \
    __builtin_amdgcn_sched_barrier(0);                                        \
    if ((KS) + 1 < NKG) {                                                     \
      asm volatile("s_waitcnt vmcnt(8) lgkmcnt(0)" ::: "memory");             \
    } else {                                                                  \
      asm volatile("s_waitcnt vmcnt(0) lgkmcnt(0)" ::: "memory");             \
    }                                                                         \
    __builtin_amdgcn_s_barrier();                                             \
    __builtin_amdgcn_sched_barrier(0);                                        \
    /* I: A_(KS+1) gloads first, then B_(KS+2) reg loads (order pinned) */    \
    if ((KS) + 1 < NKG) {                                                     \
      int h1 = ((KS) + 1) * BKS;                                              \
      gload_lds16(aq[0] + h1, &As[(P) ^ 1][(0 * 512 + tid) * 8]);             \
      gload_lds16(aq[1] + h1, &As[(P) ^ 1][(1 * 512 + tid) * 8]);             \
      __builtin_amdgcn_sched_barrier(0);                                      \
    }                                                                         \
    if ((KS) + 2 < NKG) {                                                     \
      int h2 = ((KS) + 2) * BKS;                                              \
      _Pragma("unroll")                                                       \
      for (int i = 0; i < 8; ++i)                                             \
        BV[i] = *(const float2*)(bsrc + (size_t)(h2 + i) * IDIM);             \
      __builtin_amdgcn_sched_barrier(0);                                      \
    }                                                                         \
    /* C: MFMA on buffers P */                                                \
    _Pragma("unroll")                                                         \
    for (int kk = 0; kk < 2; ++kk) {                                          \
      int jk = kk * 4 + lg4;                                                  \
      s16x8 a[4], bg, bu;                                                     \
      _Pragma("unroll")                                                       \
      for (int mr = 0; mr < 4; ++mr) {                                        \
        int r = wr * 64 + mr * 16 + l15;                                      \
        a[mr] = *(const s16x8*)&As[P][r * BKS + ((jk ^ (r & 7)) * 8)];        \
      }                                                                       \
      int rg = wc * 16 + l15;                                                 \
      int ru = 64 + rg;                                                       \
      bg = *(const s16x8*)&Bgu[P][rg * BKS + ((jk ^ ((rg >> 1) & 7)) * 8)];   \
      bu = *(const s16x8*)&Bgu[P][ru * BKS + ((jk ^ ((ru >> 1) & 7)) * 8)];   \
      _Pragma("unroll")                                                       \
      for (int mr = 0; mr < 4; ++mr) {                                        \
        accg[mr] = __builtin_amdgcn_mfma_f32_16x16x32_bf16(a[mr], bg, accg[mr], 0, 0, 0); \
        accu[mr] = __builtin_amdgcn_mfma_f32_16x16x32_bf16(a[mr], bu, accu[mr], 0, 0, 0); \
      }                                                                       \
    }                                                                         \
  }

// ---------------- kernel 5: gateup ----------------
__global__ __launch_bounds__(512, 4) void gateup_mfma(
    const unsigned short* __restrict__ xb, const float* __restrict__ gate_w,
    const float* __restrict__ up_w, const int* __restrict__ offsets,
    const int* __restrict__ pair_token, unsigned short* __restrict__ hbuf) {
    int e = blockIdx.x;
    int ntile = blockIdx.z;
    int off = offsets[e];
    int cnt = offsets[e + 1] - off;
    if (cnt <= 0) return;

    __shared__ unsigned short As[2][BM * BKS];      // 16 KB x2
    __shared__ unsigned short Bgu[2][BM * BKS];     // rows 0-63 g, 64-127 u
    __shared__ int toks[BM];

    int tid = threadIdx.x;
    int lane = tid & 63;
    int wr = (tid >> 6) >> 2, wc = (tid >> 6) & 3;
    int l15 = lane & 15, lg4 = lane >> 4;

    int mat = tid >> 8;
    int t8 = tid & 255;
    int nI2 = t8 & 31, kC = t8 >> 5;
    int brow0 = mat * 64 + nI2 * 2;
    int bslot = (kC ^ (nI2 & 7)) * 8;
    const float* bsrc = (mat ? up_w : gate_w) + (size_t)e * HDIM * IDIM
                        + (size_t)(kC * 8) * IDIM + ntile * 64 + nI2 * 2;

    for (int mt = blockIdx.y; mt * BM < cnt; mt += gridDim.y) {
        int m0 = mt * BM;
        if (tid < BM) {
            int p = m0 + tid;
            toks[tid] = pair_token[off + (p < cnt ? p : 0)];
        }
        __syncthreads();   // full drain: toks + leftover loads/stores of prev tile
        const unsigned short* aq[2];
        #pragma unroll
        for (int q = 0; q < 2; ++q) {
            int row = q * 64 + (tid >> 3);
            aq[q] = xb + (size_t)toks[row] * HDIM + (((tid & 7) ^ (row & 7)) * 8);
        }
        f32x4 accg[4] = {};
        f32x4 accu[4] = {};

        // prologue: A_0 gloads, then B_0, B_1 reg sets
        gload_lds16(aq[0], &As[0][(0 * 512 + tid) * 8]);
        gload_lds16(aq[1], &As[0][(1 * 512 + tid) * 8]);
        __builtin_amdgcn_sched_barrier(0);
        float2 BvA[8], BvB[8];
        #pragma unroll
        for (int i = 0; i < 8; ++i)
            BvA[i] = *(const float2*)(bsrc + (size_t)i * IDIM);
        __builtin_amdgcn_sched_barrier(0);
        #pragma unroll
        for (int i = 0; i < 8; ++i)
            BvB[i] = *(const float2*)(bsrc + (size_t)(BKS + i) * IDIM);
        __builtin_amdgcn_sched_barrier(0);

        for (int ks = 0; ks < NKG; ks += 2) {
            GU_STEP(ks, BvA, 0);
            GU_STEP(ks + 1, BvB, 1);
        }

        // epilogue: h = silu(g)*u
        int col = ntile * 64 + wc * 16 + l15;
        #pragma unroll
        for (int mr = 0; mr < 4; ++mr) {
            #pragma unroll
            for (int reg = 0; reg < 4; ++reg) {
                int r = m0 + wr * 64 + mr * 16 + lg4 * 4 + reg;
                if (r < cnt) {
                    float g = accg[mr][reg];
                    float u = accu[mr][reg];
                    float hv = (g / (1.f + __expf(-g))) * u;
                    hbuf[(size_t)(off + r) * IDIM + col] = f2bf(hv);
                }
            }
        }
    }
}

// pipelined step for down
#define DN_STEP(KS, BV, P)                                                    \
  {                                                                           \
    uint4 w0, w1;                                                             \
    w0.x = cvtpk(BV[0].x, BV[1].x); w0.y = cvtpk(BV[2].x, BV[3].x);           \
    w0.z = cvtpk(BV[4].x, BV[5].x); w0.w = cvtpk(BV[6].x, BV[7].x);           \
    w1.x = cvtpk(BV[0].y, BV[1].y); w1.y = cvtpk(BV[2].y, BV[3].y);           \
    w1.z = cvtpk(BV[4].y, BV[5].y); w1.w = cvtpk(BV[6].y, BV[7].y);           \
    *(uint4*)&Bd[P][brow0 * BKS + bslot] = w0;                                \
    *(uint4*)&Bd[P][(brow0 + 1) * BKS + bslot] = w1;                          \
    __builtin_amdgcn_sched_barrier(0);                                        \
    if ((KS) + 1 < NKD) {                                                     \
      asm volatile("s_waitcnt vmcnt(8) lgkmcnt(0)" ::: "memory");             \
    } else {                                                                  \
      asm volatile("s_waitcnt vmcnt(0) lgkmcnt(0)" ::: "memory");             \
    }                                                                         \
    __builtin_amdgcn_s_barrier();                                             \
    __builtin_amdgcn_sched_barrier(0);                                        \
    if ((KS) + 1 < NKD) {                                                     \
      int k1 = ((KS) + 1) * BKS;                                              \
      gload_lds16(aq[0] + k1, &As[(P) ^ 1][(0 * 512 + tid) * 8]);             \
      gload_lds16(aq[1] + k1, &As[(P) ^ 1][(1 * 512 + tid) * 8]);             \
      __builtin_amdgcn_sched_barrier(0);                                      \
    }                                                                         \
    if ((KS) + 2 < NKD) {                                                     \
      int k2 = ((KS) + 2) * BKS;                                              \
      _Pragma("unroll")                                                       \
      for (int i = 0; i < 8; ++i)                                             \
        BV[i] = *(const float2*)(bsrc + (size_t)(k2 + i) * HDIM);             \
      __builtin_amdgcn_sched_barrier(0);                                      \
    }                                                                         \
    _Pragma("unroll")                                                         \
    for (int kk = 0; kk < 2; ++kk) {                                          \
      int jk = kk * 4 + lg4;                                                  \
      s16x8 a[4], b[2];                                                       \
      _Pragma("unroll")                                                       \
      for (int mr = 0; mr < 4; ++mr) {                                        \
        int r = wr * 64 + mr * 16 + l15;                                      \
        a[mr] = *(const s16x8*)&As[P][r * BKS + ((jk ^ (r & 7)) * 8)];        \
      }                                                                       \
      _Pragma("unroll")                                                       \
      for (int nr = 0; nr < 2; ++nr) {                                        \
        int row = wc * 32 + nr * 16 + l15;                                    \
        b[nr] = *(const s16x8*)&Bd[P][row * BKS + ((jk ^ ((row >> 1) & 7)) * 8)]; \
      }                                                                       \
      _Pragma("unroll")                                                       \
      for (int mr = 0; mr < 4; ++mr)                                          \
        _Pragma("unroll")                                                     \
        for (int nr = 0; nr < 2; ++nr)                                        \
          acc[mr][nr] = __builtin_amdgcn_mfma_f32_16x16x32_bf16(a[mr], b[nr], acc[mr][nr], 0, 0, 0); \
    }                                                                         \
  }

// ---------------- kernel 6: down ----------------
__global__ __launch_bounds__(512, 4) void down_mfma(
    const unsigned short* __restrict__ hbuf, const float* __restrict__ down_w,
    const int* __restrict__ offsets, unsigned short* __restrict__ partial) {
    int e = blockIdx.x;
    int ntile = blockIdx.z;
    int off = offsets[e];
    int cnt = offsets[e + 1] - off;
    if (cnt <= 0) return;

    __shared__ unsigned short As[2][BM * BKS];      // 16 KB x2
    __shared__ unsigned short Bd[2][BM * BKS];      // [128n][64k] swz

    int tid = threadIdx.x;
    int lane = tid & 63;
    int wr = (tid >> 6) >> 2, wc = (tid >> 6) & 3;
    int l15 = lane & 15, lg4 = lane >> 4;

    int nI2 = tid & 63, kC = tid >> 6;
    int brow0 = nI2 * 2;
    int bslot = (kC ^ (nI2 & 7)) * 8;
    const float* bsrc = down_w + (size_t)e * IDIM * HDIM
                        + (size_t)(kC * 8) * HDIM + ntile * 128 + nI2 * 2;

    for (int mt = blockIdx.y; mt * BM < cnt; mt += gridDim.y) {
        int m0 = mt * BM;
        __syncthreads();   // full drain boundary between tiles
        const unsigned short* aq[2];
        #pragma unroll
        for (int q = 0; q < 2; ++q) {
            int row = q * 64 + (tid >> 3);
            int rr = m0 + row;
            if (rr >= cnt) rr = cnt - 1;
            aq[q] = hbuf + (size_t)(off + rr) * IDIM + (((tid & 7) ^ (row & 7)) * 8);
        }
        f32x4 acc[4][2] = {};

        // prologue
        gload_lds16(aq[0], &As[0][(0 * 512 + tid) * 8]);
        gload_lds16(aq[1], &As[0][(1 * 512 + tid) * 8]);
        __builtin_amdgcn_sched_barrier(0);
        float2 BvA[8], BvB[8];
        #pragma unroll
        for (int i = 0; i < 8; ++i)
            BvA[i] = *(const float2*)(bsrc + (size_t)i * HDIM);
        __builtin_amdgcn_sched_barrier(0);
        #pragma unroll
        for (int i = 0; i < 8; ++i)
            BvB[i] = *(const float2*)(bsrc + (size_t)(BKS + i) * HDIM);
        __builtin_amdgcn_sched_barrier(0);

        for (int ks = 0; ks < NKD; ks += 2) {
            DN_STEP(ks, BvA, 0);
            DN_STEP(ks + 1, BvB, 1);
        }

        #pragma unroll
        for (int mr = 0; mr < 4; ++mr)
            #pragma unroll
            for (int nr = 0; nr < 2; ++nr) {
                int col = ntile * 128 + wc * 32 + nr * 16 + l15;
                #pragma unroll
                for (int reg = 0; reg < 4; ++reg) {
                    int r = m0 + wr * 64 + mr * 16 + lg4 * 4 + reg;
                    if (r < cnt)
                        partial[(size_t)(off + r) * HDIM + col] = f2bf(acc[mr][nr][reg]);
                }
            }
    }
}

// ---------------- kernel 7: weighted reduce ----------------
__global__ __launch_bounds__(256) void reduce_kernel(
    const unsigned short* __restrict__ partial, const int* __restrict__ slot_of,
    const float* __restrict__ topk_w, float* __restrict__ out) {
    int t = blockIdx.x;
    int j8 = threadIdx.x * 8;
    __shared__ int ss[8];
    __shared__ float sw[8];
    if (threadIdx.x < 8) {
        ss[threadIdx.x] = slot_of[t * TOPK + threadIdx.x];
        sw[threadIdx.x] = topk_w[t * TOPK + threadIdx.x];
    }
    __syncthreads();
    float acc[8] = {};
    #pragma unroll
    for (int k = 0; k < TOPK; ++k) {
        u16x8 v = *(const u16x8*)&partial[(size_t)ss[k] * HDIM + j8];
        float w = sw[k];
        #pragma unroll
        for (int i = 0; i < 8; ++i)
            acc[i] = fmaf(w, bf_to_f((unsigned short)v[i]), acc[i]);
    }
    float4 o0 = {acc[0], acc[1], acc[2], acc[3]};
    float4 o1 = {acc[4], acc[5], acc[6], acc[7]};
    *(float4*)&out[(size_t)t * HDIM + j8] = o0;
    *(float4*)&out[(size_t)t * HDIM + j8 + 4] = o1;
}

extern "C" void kernel_launch(void* const* d_in, const int* in_sizes, int n_in,
                              void* d_out, int out_size, void* d_ws, size_t ws_size,
                              hipStream_t stream) {
    const float* x  = (const float*)d_in[0];
    const float* rw = (const float*)d_in[1];
    const float* gw = (const float*)d_in[2];
    const float* uw = (const float*)d_in[3];
    const float* dw = (const float*)d_in[4];
    float* out = (float*)d_out;
    float* logits = out + OUT_OFF;

    char* ws = (char*)d_ws;
    int*   topk_idx   = (int*)(ws + WS_TOPK_IDX);
    float* topk_w     = (float*)(ws + WS_TOPK_W);
    int*   pair_token = (int*)(ws + WS_PAIR_TOK);
    int*   slot_of    = (int*)(ws + WS_SLOT_OF);
    int*   counts     = (int*)(ws + WS_COUNTS);
    int*   offsets    = (int*)(ws + WS_OFFSETS);
    int*   cursor     = (int*)(ws + WS_CURSOR);
    unsigned short* hbuf    = (unsigned short*)(ws + WS_H);
    unsigned short* partial = (unsigned short*)(ws + WS_PARTIAL);
    unsigned short* xb      = (unsigned short*)(ws + WS_XB);

    hipMemsetAsync(counts, 0, NEXP * sizeof(int), stream);
    xbf_kernel<<<T_TOK * HDIM / (256 * 8), 256, 0, stream>>>(x, xb);
    router_kernel<<<T_TOK / 4, 256, 0, stream>>>(x, rw, logits);
    topk_kernel<<<T_TOK, 64, 0, stream>>>(logits, topk_idx, topk_w, counts);
    scan_kernel<<<1, 64, 0, stream>>>(counts, offsets, cursor);
    scatter_kernel<<<NPAIR / 256, 256, 0, stream>>>(topk_idx, offsets, cursor, pair_token, slot_of);
    gateup_mfma<<<dim3(NEXP, 4, IDIM / 64), 512, 0, stream>>>(xb, gw, uw, offsets, pair_token, hbuf);
    down_mfma<<<dim3(NEXP, 4, HDIM / 128), 512, 0, stream>>>(hbuf, dw, offsets, partial);
    reduce_kernel<<<dim3(T_TOK, 1), 256, 0, stream>>>(partial, slot_of, topk_w, out);
}

// Round 7
// 726.534 us; speedup vs baseline: 1.0142x; 1.0142x over previous
//
#include <hip/hip_runtime.h>
#include <hip/hip_bf16.h>

typedef __hip_bfloat16 bf16;
typedef short s16x8 __attribute__((ext_vector_type(8)));
typedef unsigned short u16x8 __attribute__((ext_vector_type(8)));
typedef float f32x4 __attribute__((ext_vector_type(4)));

#define T_TOK 2048
#define HDIM  2048
#define NEXP  64
#define IDIM  768
#define TOPK  8
#define OUT_OFF (T_TOK * HDIM)
#define NPAIR (T_TOK * TOPK)

#define WS_TOPK_IDX  0
#define WS_TOPK_W    (64 * 1024)
#define WS_PAIR_TOK  (128 * 1024)
#define WS_SLOT_OF   (192 * 1024)
#define WS_COUNTS    (256 * 1024)
#define WS_OFFSETS   (257 * 1024)
#define WS_CURSOR    (258 * 1024)
#define WS_H         (1024 * 1024)             // bf16 [NPAIR][IDIM]
#define WS_PARTIAL   (WS_H + (size_t)NPAIR * IDIM * 2)  // bf16 [NPAIR][HDIM]
#define WS_XB        WS_PARTIAL                // bf16 [T][H] (dead before partial written)

__device__ __forceinline__ float bf_to_f(unsigned short u) {
    return __uint_as_float(((unsigned int)u) << 16);
}
__device__ __forceinline__ unsigned short f2bf(float f) {
    unsigned int u = __float_as_uint(f);
    unsigned int r = (u + 0x7FFFu + ((u >> 16) & 1u)) >> 16;
    return (unsigned short)r;
}
__device__ __forceinline__ unsigned cvtpk(float lo, float hi) {
    unsigned r;
    asm("v_cvt_pk_bf16_f32 %0, %1, %2" : "=v"(r) : "v"(lo), "v"(hi));
    return r;
}

typedef const __attribute__((address_space(1))) unsigned int* gas_ptr;
typedef __attribute__((address_space(3))) unsigned int* las_ptr;
__device__ __forceinline__ void gload_lds16(const void* g, void* l) {
    __builtin_amdgcn_global_load_lds((gas_ptr)g, (las_ptr)l, 16, 0, 0);
}

// ---------------- kernel 0: x fp32 -> bf16 ----------------
__global__ __launch_bounds__(256) void xbf_kernel(const float* __restrict__ x,
                                                  unsigned short* __restrict__ xb) {
    int i = blockIdx.x * 256 + threadIdx.x;
    const float4* src = (const float4*)x + (size_t)i * 2;
    float4 a = src[0], b = src[1];
    u16x8 o;
    o[0] = f2bf(a.x); o[1] = f2bf(a.y); o[2] = f2bf(a.z); o[3] = f2bf(a.w);
    o[4] = f2bf(b.x); o[5] = f2bf(b.y); o[6] = f2bf(b.z); o[7] = f2bf(b.w);
    ((u16x8*)xb)[i] = o;
}

// ---------------- kernel 1: router logits ----------------
__global__ __launch_bounds__(256) void router_kernel(
    const float* __restrict__ x, const float* __restrict__ rw,
    float* __restrict__ logits) {
    int wave = threadIdx.x >> 6;
    int lane = threadIdx.x & 63;
    int t = blockIdx.x * 4 + wave;
    const float4* x4 = (const float4*)(x + (size_t)t * HDIM);
    float acc = 0.f;
    for (int h4 = 0; h4 < HDIM / 4; ++h4) {
        float4 xv = x4[h4];
        int h = h4 * 4;
        acc = fmaf(xv.x, rw[(h + 0) * NEXP + lane], acc);
        acc = fmaf(xv.y, rw[(h + 1) * NEXP + lane], acc);
        acc = fmaf(xv.z, rw[(h + 2) * NEXP + lane], acc);
        acc = fmaf(xv.w, rw[(h + 3) * NEXP + lane], acc);
    }
    logits[t * NEXP + lane] = acc;
}

// ---------------- kernel 2: softmax + top-8 ----------------
__global__ __launch_bounds__(64) void topk_kernel(
    const float* __restrict__ logits, int* __restrict__ topk_idx,
    float* __restrict__ topk_w, int* __restrict__ counts) {
    int t = blockIdx.x;
    int lane = threadIdx.x;
    float lg = logits[t * NEXP + lane];
    float mx = lg;
    for (int off = 32; off; off >>= 1) mx = fmaxf(mx, __shfl_xor(mx, off));
    float ex = expf(lg - mx);
    float sum = ex;
    for (int off = 32; off; off >>= 1) sum += __shfl_xor(sum, off);
    float prob = ex / sum;

    float pr = prob;
    float myv = 0.f;
    int myidx = 0;
    float ksum = 0.f;
    for (int k = 0; k < TOPK; ++k) {
        float v = pr;
        int idx = lane;
        for (int off = 32; off; off >>= 1) {
            float ov = __shfl_xor(v, off);
            int oi = __shfl_xor(idx, off);
            if (ov > v || (ov == v && oi < idx)) { v = ov; idx = oi; }
        }
        ksum += v;
        if (lane == k) { myidx = idx; myv = v; }
        if (lane == idx) pr = -1.f;
    }
    if (lane < TOPK) {
        topk_idx[t * TOPK + lane] = myidx;
        topk_w[t * TOPK + lane] = myv / ksum;
        atomicAdd(&counts[myidx], 1);
    }
}

// ---------------- kernel 3: scan ----------------
__global__ __launch_bounds__(64) void scan_kernel(
    const int* __restrict__ counts, int* __restrict__ offsets, int* __restrict__ cursor) {
    int lane = threadIdx.x;
    int c = counts[lane];
    int incl = c;
    for (int off = 1; off < 64; off <<= 1) {
        int tt = __shfl_up(incl, off);
        if (lane >= off) incl += tt;
    }
    offsets[lane] = incl - c;
    if (lane == 63) offsets[64] = incl;
    cursor[lane] = 0;
}

// ---------------- kernel 4: scatter ----------------
__global__ __launch_bounds__(256) void scatter_kernel(
    const int* __restrict__ topk_idx, const int* __restrict__ offsets,
    int* __restrict__ cursor, int* __restrict__ pair_token, int* __restrict__ slot_of) {
    int i = blockIdx.x * 256 + threadIdx.x;
    if (i >= NPAIR) return;
    int t = i >> 3;
    int e = topk_idx[i];
    int pos = atomicAdd(&cursor[e], 1);
    int slot = offsets[e] + pos;
    pair_token[slot] = t;
    slot_of[i] = slot;
}

// ============== MFMA grouped GEMMs: 1024 thr, wide B tiles ==============
#define BM   128
#define BKS  64
#define NZG  6     // gateup ntiles (128 i-cols each)
#define NZD  8     // down ntiles (256 h-cols each)
#define NKG  (HDIM / BKS)   // 32
#define NKD  (IDIM / BKS)   // 12

// ---------------- kernel 5: gateup ----------------
// 1024 thr = 16 waves (2wr x 8wc); wave = 64m x 16c, both mats.
// B: 128 i-cols x 2 mats staged fp32->bf16; per-k-row read = 512 B contiguous
//    per mat. XCD-chunked grid: same-XCD blocks read adjacent col-chunks.
__global__ __launch_bounds__(1024, 4) void gateup_mfma(
    const unsigned short* __restrict__ xb, const float* __restrict__ gate_w,
    const float* __restrict__ up_w, const int* __restrict__ offsets,
    const int* __restrict__ pair_token, unsigned short* __restrict__ hbuf) {
    int id = blockIdx.x;
    int xcd = id & 7, rid = id >> 3;
    int ntile = rid % NZG;
    int y = (rid / NZG) & 1;
    int e = (rid / (2 * NZG)) * 8 + xcd;
    int off = offsets[e];
    int cnt = offsets[e + 1] - off;
    if (cnt <= 0) return;

    __shared__ unsigned short As[2][BM * BKS];       // 2 x 16 KB
    __shared__ unsigned short Bgu[2][256 * BKS];     // 2 x 32 KB (g rows 0-127, u 128-255)
    __shared__ int toks[BM];

    int tid = threadIdx.x;
    int lane = tid & 63;
    int w = tid >> 6;
    int wr = w & 1, wc = w >> 1;          // wc 0..7
    int l15 = lane & 15, lg4 = lane >> 4;

    // B staging map: 1024 thr = 2 mat x 64 n-pair x 8 k-chunk
    int mat = tid >> 9;
    int s = tid & 511;
    int nI2 = s & 63, kC = s >> 6;
    int brow0 = mat * 128 + nI2 * 2;
    int bslot = (kC ^ (nI2 & 7)) * 8;
    const float* bsrc = (mat ? up_w : gate_w) + (size_t)e * HDIM * IDIM
                        + (size_t)(kC * 8) * IDIM + ntile * 128 + nI2 * 2;

    int arow = tid >> 3;
    int ajx = (tid & 7) ^ (arow & 7);

    for (int mt = y; mt * BM < cnt; mt += 2) {
        int m0 = mt * BM;
        if (tid < BM) {
            int p = m0 + tid;
            toks[tid] = pair_token[off + (p < cnt ? p : 0)];
        }
        __syncthreads();   // toks ready + LDS reuse guard
        const unsigned short* aq = xb + (size_t)toks[arow] * HDIM + ajx * 8;
        f32x4 accg[4] = {};
        f32x4 accu[4] = {};

        // prologue: A_0 + B_0 regs
        gload_lds16(aq, &As[0][tid * 8]);
        float2 Bv[8];
        #pragma unroll
        for (int i = 0; i < 8; ++i)
            Bv[i] = *(const float2*)(bsrc + (size_t)i * IDIM);

        for (int ks = 0; ks < NKG; ++ks) {
            int p = ks & 1;
            {   // W: cvt + b128 write B_ks
                uint4 w0, w1;
                w0.x = cvtpk(Bv[0].x, Bv[1].x); w0.y = cvtpk(Bv[2].x, Bv[3].x);
                w0.z = cvtpk(Bv[4].x, Bv[5].x); w0.w = cvtpk(Bv[6].x, Bv[7].x);
                w1.x = cvtpk(Bv[0].y, Bv[1].y); w1.y = cvtpk(Bv[2].y, Bv[3].y);
                w1.z = cvtpk(Bv[4].y, Bv[5].y); w1.w = cvtpk(Bv[6].y, Bv[7].y);
                *(uint4*)&Bgu[p][brow0 * BKS + bslot] = w0;
                *(uint4*)&Bgu[p][(brow0 + 1) * BKS + bslot] = w1;
            }
            __syncthreads();   // drains A_ks gloads (1 step old) + B writes
            if (ks + 1 < NKG) {
                int h1 = (ks + 1) * BKS;
                gload_lds16(aq + h1, &As[p ^ 1][tid * 8]);
                #pragma unroll
                for (int i = 0; i < 8; ++i)
                    Bv[i] = *(const float2*)(bsrc + (size_t)(h1 + i) * IDIM);
            }
            // C: MFMA on buffers p
            #pragma unroll
            for (int kk = 0; kk < 2; ++kk) {
                int jk = kk * 4 + lg4;
                s16x8 a[4], bg, bu;
                #pragma unroll
                for (int mr = 0; mr < 4; ++mr) {
                    int r = wr * 64 + mr * 16 + l15;
                    a[mr] = *(const s16x8*)&As[p][r * BKS + ((jk ^ (r & 7)) * 8)];
                }
                int rg = wc * 16 + l15;
                int ru = 128 + rg;
                bg = *(const s16x8*)&Bgu[p][rg * BKS + ((jk ^ ((rg >> 1) & 7)) * 8)];
                bu = *(const s16x8*)&Bgu[p][ru * BKS + ((jk ^ ((ru >> 1) & 7)) * 8)];
                #pragma unroll
                for (int mr = 0; mr < 4; ++mr) {
                    accg[mr] = __builtin_amdgcn_mfma_f32_16x16x32_bf16(a[mr], bg, accg[mr], 0, 0, 0);
                    accu[mr] = __builtin_amdgcn_mfma_f32_16x16x32_bf16(a[mr], bu, accu[mr], 0, 0, 0);
                }
            }
        }

        // epilogue: h = silu(g)*u
        int col = ntile * 128 + wc * 16 + l15;
        #pragma unroll
        for (int mr = 0; mr < 4; ++mr) {
            #pragma unroll
            for (int reg = 0; reg < 4; ++reg) {
                int r = m0 + wr * 64 + mr * 16 + lg4 * 4 + reg;
                if (r < cnt) {
                    float g = accg[mr][reg];
                    float u = accu[mr][reg];
                    float hv = (g / (1.f + __expf(-g))) * u;
                    hbuf[(size_t)(off + r) * IDIM + col] = f2bf(hv);
                }
            }
        }
        __syncthreads();
    }
}

// ---------------- kernel 6: down ----------------
// 1024 thr = 16 waves (2wr x 8wc); wave = 64m x 32n; BN=256.
// Per-k-row read = 1024 B contiguous.
__global__ __launch_bounds__(1024, 4) void down_mfma(
    const unsigned short* __restrict__ hbuf, const float* __restrict__ down_w,
    const int* __restrict__ offsets, unsigned short* __restrict__ partial) {
    int id = blockIdx.x;
    int xcd = id & 7, rid = id >> 3;
    int ntile = rid % NZD;
    int y = (rid / NZD) & 1;
    int e = (rid / (2 * NZD)) * 8 + xcd;
    int off = offsets[e];
    int cnt = offsets[e + 1] - off;
    if (cnt <= 0) return;

    __shared__ unsigned short As[2][BM * BKS];       // 2 x 16 KB
    __shared__ unsigned short Bd[2][256 * BKS];      // 2 x 32 KB

    int tid = threadIdx.x;
    int lane = tid & 63;
    int w = tid >> 6;
    int wr = w & 1, wc = w >> 1;          // wc 0..7
    int l15 = lane & 15, lg4 = lane >> 4;

    // B staging: 1024 thr = 128 n-pair x 8 k-chunk
    int nI2 = tid & 127, kC = tid >> 7;
    int brow0 = nI2 * 2;
    int bslot = (kC ^ (nI2 & 7)) * 8;
    const float* bsrc = down_w + (size_t)e * IDIM * HDIM
                        + (size_t)(kC * 8) * HDIM + ntile * 256 + nI2 * 2;

    int arow = tid >> 3;
    int ajx = (tid & 7) ^ (arow & 7);

    for (int mt = y; mt * BM < cnt; mt += 2) {
        int m0 = mt * BM;
        __syncthreads();   // LDS reuse guard
        int rr = m0 + arow;
        if (rr >= cnt) rr = cnt - 1;
        const unsigned short* aq = hbuf + (size_t)(off + rr) * IDIM + ajx * 8;
        f32x4 acc[4][2] = {};

        // prologue
        gload_lds16(aq, &As[0][tid * 8]);
        float2 Bv[8];
        #pragma unroll
        for (int i = 0; i < 8; ++i)
            Bv[i] = *(const float2*)(bsrc + (size_t)i * HDIM);

        for (int ks = 0; ks < NKD; ++ks) {
            int p = ks & 1;
            {
                uint4 w0, w1;
                w0.x = cvtpk(Bv[0].x, Bv[1].x); w0.y = cvtpk(Bv[2].x, Bv[3].x);
                w0.z = cvtpk(Bv[4].x, Bv[5].x); w0.w = cvtpk(Bv[6].x, Bv[7].x);
                w1.x = cvtpk(Bv[0].y, Bv[1].y); w1.y = cvtpk(Bv[2].y, Bv[3].y);
                w1.z = cvtpk(Bv[4].y, Bv[5].y); w1.w = cvtpk(Bv[6].y, Bv[7].y);
                *(uint4*)&Bd[p][brow0 * BKS + bslot] = w0;
                *(uint4*)&Bd[p][(brow0 + 1) * BKS + bslot] = w1;
            }
            __syncthreads();
            if (ks + 1 < NKD) {
                int k1 = (ks + 1) * BKS;
                gload_lds16(aq + k1, &As[p ^ 1][tid * 8]);
                #pragma unroll
                for (int i = 0; i < 8; ++i)
                    Bv[i] = *(const float2*)(bsrc + (size_t)(k1 + i) * HDIM);
            }
            #pragma unroll
            for (int kk = 0; kk < 2; ++kk) {
                int jk = kk * 4 + lg4;
                s16x8 a[4], b[2];
                #pragma unroll
                for (int mr = 0; mr < 4; ++mr) {
                    int r = wr * 64 + mr * 16 + l15;
                    a[mr] = *(const s16x8*)&As[p][r * BKS + ((jk ^ (r & 7)) * 8)];
                }
                #pragma unroll
                for (int nr = 0; nr < 2; ++nr) {
                    int row = wc * 32 + nr * 16 + l15;
                    b[nr] = *(const s16x8*)&Bd[p][row * BKS + ((jk ^ ((row >> 1) & 7)) * 8)];
                }
                #pragma unroll
                for (int mr = 0; mr < 4; ++mr)
                    #pragma unroll
                    for (int nr = 0; nr < 2; ++nr)
                        acc[mr][nr] = __builtin_amdgcn_mfma_f32_16x16x32_bf16(
                            a[mr], b[nr], acc[mr][nr], 0, 0, 0);
            }
        }

        #pragma unroll
        for (int mr = 0; mr < 4; ++mr)
            #pragma unroll
            for (int nr = 0; nr < 2; ++nr) {
                int col = ntile * 256 + wc * 32 + nr * 16 + l15;
                #pragma unroll
                for (int reg = 0; reg < 4; ++reg) {
                    int r = m0 + wr * 64 + mr * 16 + lg4 * 4 + reg;
                    if (r < cnt)
                        partial[(size_t)(off + r) * HDIM + col] = f2bf(acc[mr][nr][reg]);
                }
            }
        __syncthreads();
    }
}

// ---------------- kernel 7: weighted reduce ----------------
__global__ __launch_bounds__(256) void reduce_kernel(
    const unsigned short* __restrict__ partial, const int* __restrict__ slot_of,
    const float* __restrict__ topk_w, float* __restrict__ out) {
    int t = blockIdx.x;
    int j8 = threadIdx.x * 8;
    __shared__ int ss[8];
    __shared__ float sw[8];
    if (threadIdx.x < 8) {
        ss[threadIdx.x] = slot_of[t * TOPK + threadIdx.x];
        sw[threadIdx.x] = topk_w[t * TOPK + threadIdx.x];
    }
    __syncthreads();
    float acc[8] = {};
    #pragma unroll
    for (int k = 0; k < TOPK; ++k) {
        u16x8 v = *(const u16x8*)&partial[(size_t)ss[k] * HDIM + j8];
        float w = sw[k];
        #pragma unroll
        for (int i = 0; i < 8; ++i)
            acc[i] = fmaf(w, bf_to_f((unsigned short)v[i]), acc[i]);
    }
    float4 o0 = {acc[0], acc[1], acc[2], acc[3]};
    float4 o1 = {acc[4], acc[5], acc[6], acc[7]};
    *(float4*)&out[(size_t)t * HDIM + j8] = o0;
    *(float4*)&out[(size_t)t * HDIM + j8 + 4] = o1;
}

extern "C" void kernel_launch(void* const* d_in, const int* in_sizes, int n_in,
                              void* d_out, int out_size, void* d_ws, size_t ws_size,
                              hipStream_t stream) {
    const float* x  = (const float*)d_in[0];
    const float* rw = (const float*)d_in[1];
    const float* gw = (const float*)d_in[2];
    const float* uw = (const float*)d_in[3];
    const float* dw = (const float*)d_in[4];
    float* out = (float*)d_out;
    float* logits = out + OUT_OFF;

    char* ws = (char*)d_ws;
    int*   topk_idx   = (int*)(ws + WS_TOPK_IDX);
    float* topk_w     = (float*)(ws + WS_TOPK_W);
    int*   pair_token = (int*)(ws + WS_PAIR_TOK);
    int*   slot_of    = (int*)(ws + WS_SLOT_OF);
    int*   counts     = (int*)(ws + WS_COUNTS);
    int*   offsets    = (int*)(ws + WS_OFFSETS);
    int*   cursor     = (int*)(ws + WS_CURSOR);
    unsigned short* hbuf    = (unsigned short*)(ws + WS_H);
    unsigned short* partial = (unsigned short*)(ws + WS_PARTIAL);
    unsigned short* xb      = (unsigned short*)(ws + WS_XB);

    hipMemsetAsync(counts, 0, NEXP * sizeof(int), stream);
    xbf_kernel<<<T_TOK * HDIM / (256 * 8), 256, 0, stream>>>(x, xb);
    router_kernel<<<T_TOK / 4, 256, 0, stream>>>(x, rw, logits);
    topk_kernel<<<T_TOK, 64, 0, stream>>>(logits, topk_idx, topk_w, counts);
    scan_kernel<<<1, 64, 0, stream>>>(counts, offsets, cursor);
    scatter_kernel<<<NPAIR / 256, 256, 0, stream>>>(topk_idx, offsets, cursor, pair_token, slot_of);
    gateup_mfma<<<NEXP * 2 * NZG, 1024, 0, stream>>>(xb, gw, uw, offsets, pair_token, hbuf);
    down_mfma<<<NEXP * 2 * NZD, 1024, 0, stream>>>(hbuf, dw, offsets, partial);
    reduce_kernel<<<dim3(T_TOK, 1), 256, 0, stream>>>(partial, slot_of, topk_w, out);
}